// Round 7
// baseline (878.230 us; speedup 1.0000x reference)
//
#include <hip/hip_runtime.h>
#include <hip/hip_bf16.h>

// out = elu(segment_sum(typed_linear(x[src], W_w, etype), dst) + x@W_res + b_res)
// (attention path of the reference is dead code)
//
// FUSED: per 64-node block, for each type g: accumulate agg[dl][:] =
// sum x[src] over type-g edges (LDS f32 atomics, xb is L2/L3-resident 12.8MB),
// then MFMA agg x W_g from L2-hot Wb, accumulating in registers over all 9
// groups (g=8 = residual, A read from xb directly). No y intermediate at all.

#define CAPB 1536   // per 64-node bucket capacity (mean ~1024, +16 sigma)
#define CHUNK 2048  // edges per binning block
#define NBKT 1024   // coarse bucket array size (782 used)

typedef __bf16 bf16x8 __attribute__((ext_vector_type(8)));
typedef float f32x4 __attribute__((ext_vector_type(4)));

__device__ __forceinline__ void gload_lds16(const void* g, void* l) {
  __builtin_amdgcn_global_load_lds(
      (const __attribute__((address_space(1))) unsigned int*)g,
      (__attribute__((address_space(3))) unsigned int*)l, 16, 0, 0);
}

__device__ __forceinline__ float uflo(unsigned u) { return __uint_as_float(u << 16); }
__device__ __forceinline__ float ufhi(unsigned u) { return __uint_as_float(u & 0xffff0000u); }

// ---------------- CSR pass A: coarse binning by dst>>6 ----------------
// pack = (src<<9) | (et<<6) | (dst&63);  key = pack & 511 = (et,dl)
__global__ __launch_bounds__(512) void k_binA(
    const int* __restrict__ src, const int* __restrict__ dst,
    const int* __restrict__ et, int* __restrict__ gCount,
    int* __restrict__ bucketBuf, int E) {
  __shared__ int buf[CHUNK];
  __shared__ unsigned short bkt[CHUNK];
  __shared__ int h[NBKT], ls[NBKT], cur[NBKT], gb[NBKT];
  __shared__ int sc[512];
  const int tid = threadIdx.x;
  const int base = blockIdx.x * CHUNK;
  const int cnt = min(CHUNK, E - base);

  h[tid] = 0; h[tid + 512] = 0;
  __syncthreads();
  for (int j = tid; j < cnt; j += 512) atomicAdd(&h[dst[base + j] >> 6], 1);
  __syncthreads();
  int a0 = h[2 * tid], a1 = h[2 * tid + 1];
  sc[tid] = a0 + a1;
  __syncthreads();
  for (int off = 1; off < 512; off <<= 1) {
    int t = (tid >= off) ? sc[tid - off] : 0;
    __syncthreads();
    if (tid >= off) sc[tid] += t;
    __syncthreads();
  }
  int ex = sc[tid] - a0 - a1;
  ls[2 * tid] = ex;       cur[2 * tid] = ex;
  ls[2 * tid + 1] = ex + a0; cur[2 * tid + 1] = ex + a0;
  gb[2 * tid] = (a0 > 0) ? atomicAdd(&gCount[2 * tid], a0) : 0;
  gb[2 * tid + 1] = (a1 > 0) ? atomicAdd(&gCount[2 * tid + 1], a1) : 0;
  __syncthreads();
  for (int j = tid; j < cnt; j += 512) {
    int e = base + j;
    int d = dst[e];
    int b = d >> 6;
    int pos = atomicAdd(&cur[b], 1);
    buf[pos] = (src[e] << 9) | (et[e] << 6) | (d & 63);
    bkt[pos] = (unsigned short)b;
  }
  __syncthreads();
  for (int j = tid; j < cnt; j += 512) {
    int b = bkt[j];
    int pos = gb[b] + (j - ls[b]);
    if (pos < CAPB) bucketBuf[b * CAPB + pos] = buf[j];
  }
}

// exclusive scan of 1024 coarse counts (pair trick)
__global__ __launch_bounds__(512) void k_scanC(
    const int* __restrict__ gCount, int* __restrict__ coarseBase) {
  __shared__ int sc[512];
  int tid = threadIdx.x;
  int a0 = gCount[2 * tid], a1 = gCount[2 * tid + 1];
  sc[tid] = a0 + a1;
  __syncthreads();
  for (int off = 1; off < 512; off <<= 1) {
    int t = (tid >= off) ? sc[tid - off] : 0;
    __syncthreads();
    if (tid >= off) sc[tid] += t;
    __syncthreads();
  }
  int ex = sc[tid] - a0 - a1;
  coarseBase[2 * tid] = ex;
  coarseBase[2 * tid + 1] = ex + a0;
}

// ---------------- CSR pass B: sort bucket by (et,dl); emit tseg ----------------
__global__ __launch_bounds__(512) void k_sortB(
    const int* __restrict__ bucketBuf, const int* __restrict__ gCount,
    const int* __restrict__ coarseBase, int* __restrict__ packed2,
    int* __restrict__ tseg) {
  __shared__ int raw[CAPB];
  __shared__ int h[512], bs[512], cur[512], scn[512];
  const int b = blockIdx.x;
  const int tid = threadIdx.x;
  const int cnt = min(gCount[b], CAPB);
  const int base = coarseBase[b];

  h[tid] = 0;
  __syncthreads();
  for (int j = tid; j < cnt; j += 512) {
    int p = bucketBuf[b * CAPB + j];
    raw[j] = p;
    atomicAdd(&h[p & 511], 1);
  }
  __syncthreads();
  scn[tid] = h[tid];
  __syncthreads();
  for (int off = 1; off < 512; off <<= 1) {
    int t = (tid >= off) ? scn[tid - off] : 0;
    __syncthreads();
    if (tid >= off) scn[tid] += t;
    __syncthreads();
  }
  bs[tid] = scn[tid] - h[tid];
  cur[tid] = bs[tid];
  __syncthreads();
  if (tid < 8) tseg[b * 9 + tid] = base + bs[tid << 6];
  if (tid == 8) tseg[b * 9 + 8] = base + cnt;
  for (int j = tid; j < cnt; j += 512) {
    int p = raw[j];
    int pos = atomicAdd(&cur[p & 511], 1);
    packed2[base + pos] = ((p >> 9) << 6) | (p & 63);  // (src<<6)|dl
  }
}

// ---------------- converts ----------------
__global__ void k_xcast(const float* __restrict__ x, ushort4* __restrict__ xb4,
                        int n4, int npad4) {
  int i = blockIdx.x * 256 + threadIdx.x;
  if (i >= npad4) return;
  ushort4 o = {0, 0, 0, 0};
  if (i < n4) {
    f32x4 v = *(const f32x4*)(x + i * 4);
    __hip_bfloat16 h0 = __float2bfloat16(v[0]), h1 = __float2bfloat16(v[1]);
    __hip_bfloat16 h2 = __float2bfloat16(v[2]), h3 = __float2bfloat16(v[3]);
    o.x = *(unsigned short*)&h0; o.y = *(unsigned short*)&h1;
    o.z = *(unsigned short*)&h2; o.w = *(unsigned short*)&h3;
  }
  xb4[i] = o;
}

// Wb row-major [1152 n][128 k]: n<1024 -> W_w[n>>7][k][n&127], else W_res[k][n&127]
__global__ void k_wb(const float* __restrict__ Ww, const float* __restrict__ Wres,
                     __hip_bfloat16* __restrict__ Wb) {
  int o = blockIdx.x * 256 + threadIdx.x;
  if (o >= 1152 * 128) return;
  int nn = o >> 7, kk = o & 127;
  float v = (nn < 1024) ? Ww[(nn >> 7) * 16384 + kk * 128 + (nn & 127)]
                        : Wres[kk * 128 + (nn & 127)];
  Wb[o] = __float2bfloat16(v);
}

// ---------------- fused aggregate + GEMM + epilogue ----------------
// 64 nodes/block, 512 threads = 8 waves (4 wr x 2 wc), each wave 16 rows x 64 cols.
// agg layout per row (136 dwords): lo col 2l at dword (l ^ 4*(dl&7)), hi col 2l+1
// at 68 + (l ^ 4*(dl&7))  -> atomics land 2 lanes/bank; af reads are aligned b128.
__global__ __launch_bounds__(512, 4) void k_fused(
    const unsigned* __restrict__ xbu, const __hip_bfloat16* __restrict__ Wb,
    const int* __restrict__ packed2, const int* __restrict__ tseg,
    const float* __restrict__ bres, float* __restrict__ out, int N) {
  __shared__ __align__(16) float agg[64 * 136];
  const int tid = threadIdx.x;
  const int lane = tid & 63;
  const int wid = tid >> 6;
  const int wr = wid >> 1, wc = wid & 1;
  const int b = blockIdx.x, node0 = b * 64;
  const char* wbb = (const char*)Wb;
  const char* xbb = (const char*)xbu;

  f32x4 acc[4] = {};

  const int r = wr * 16 + (lane & 15);       // this lane's A row (0..63)
  const int kh = (lane >> 4);                // k-subgroup 0..3
  const int rx = (r & 7) << 2;               // agg XOR

  for (int g = 0; g < 8; ++g) {
    // zero agg
#pragma unroll
    for (int i = 0; i < 5; ++i) {
      int c = i * 512 + tid;
      if (c < 64 * 136 / 4) ((f32x4*)agg)[c] = (f32x4){0.f, 0.f, 0.f, 0.f};
    }
    __syncthreads();
    // accumulate type-g edges
    int s = tseg[b * 9 + g], eend = tseg[b * 9 + g + 1];
    int len = eend - s;
    int e = s + ((len * wid) >> 3);
    const int e1 = s + ((len * (wid + 1)) >> 3);
    for (; e + 3 < e1; e += 4) {
      int p0 = packed2[e], p1 = packed2[e + 1], p2 = packed2[e + 2], p3 = packed2[e + 3];
      unsigned u0 = xbu[(p0 >> 6) * 64 + lane];
      unsigned u1 = xbu[(p1 >> 6) * 64 + lane];
      unsigned u2 = xbu[(p2 >> 6) * 64 + lane];
      unsigned u3 = xbu[(p3 >> 6) * 64 + lane];
      int d0 = p0 & 63, d1 = p1 & 63, d2 = p2 & 63, d3 = p3 & 63;
      int o0 = d0 * 136 + (lane ^ ((d0 & 7) << 2));
      int o1 = d1 * 136 + (lane ^ ((d1 & 7) << 2));
      int o2 = d2 * 136 + (lane ^ ((d2 & 7) << 2));
      int o3 = d3 * 136 + (lane ^ ((d3 & 7) << 2));
      atomicAdd(&agg[o0], uflo(u0)); atomicAdd(&agg[o0 + 68], ufhi(u0));
      atomicAdd(&agg[o1], uflo(u1)); atomicAdd(&agg[o1 + 68], ufhi(u1));
      atomicAdd(&agg[o2], uflo(u2)); atomicAdd(&agg[o2 + 68], ufhi(u2));
      atomicAdd(&agg[o3], uflo(u3)); atomicAdd(&agg[o3 + 68], ufhi(u3));
    }
    for (; e < e1; ++e) {
      int p = packed2[e];
      unsigned u = xbu[(p >> 6) * 64 + lane];
      int d = p & 63;
      int o = d * 136 + (lane ^ ((d & 7) << 2));
      atomicAdd(&agg[o], uflo(u)); atomicAdd(&agg[o + 68], ufhi(u));
    }
    __syncthreads();
    // MFMA group g: af from agg (cvt f32->bf16), bf straight from L2-hot Wb
#pragma unroll
    for (int ks = 0; ks < 4; ++ks) {
      int j = (ks * 16 + kh * 4) ^ rx;
      f32x4 lo = *(const f32x4*)(agg + r * 136 + j);
      f32x4 hi = *(const f32x4*)(agg + r * 136 + 68 + j);
      bf16x8 af;
      af[0] = (__bf16)lo[0]; af[1] = (__bf16)hi[0];
      af[2] = (__bf16)lo[1]; af[3] = (__bf16)hi[1];
      af[4] = (__bf16)lo[2]; af[5] = (__bf16)hi[2];
      af[6] = (__bf16)lo[3]; af[7] = (__bf16)hi[3];
#pragma unroll
      for (int ni = 0; ni < 4; ++ni) {
        int col = wc * 64 + ni * 16 + (lane & 15);
        bf16x8 bf = *(const bf16x8*)(wbb + (long)(g * 128 + col) * 256 + ks * 64 + (kh << 4));
        acc[ni] = __builtin_amdgcn_mfma_f32_16x16x32_bf16(af, bf, acc[ni], 0, 0, 0);
      }
    }
    __syncthreads();
  }
  // g = 8: residual, A rows straight from xb (already bf16)
#pragma unroll
  for (int ks = 0; ks < 4; ++ks) {
    bf16x8 af = *(const bf16x8*)(xbb + (long)(node0 + r) * 256 + ks * 64 + (kh << 4));
#pragma unroll
    for (int ni = 0; ni < 4; ++ni) {
      int col = wc * 64 + ni * 16 + (lane & 15);
      bf16x8 bf = *(const bf16x8*)(wbb + (long)(1024 + col) * 256 + ks * 64 + (kh << 4));
      acc[ni] = __builtin_amdgcn_mfma_f32_16x16x32_bf16(af, bf, acc[ni], 0, 0, 0);
    }
  }
  // epilogue: bias + ELU; C/D layout col=lane&15, row=(lane>>4)*4+q
#pragma unroll
  for (int ni = 0; ni < 4; ++ni) {
    int col = wc * 64 + ni * 16 + (lane & 15);
    float bias = bres[col];
    int rowb = node0 + wr * 16 + (kh << 2);
    f32x4 v = acc[ni];
#pragma unroll
    for (int q = 0; q < 4; ++q) {
      int row = rowb + q;
      if (row < N) {
        float o = v[q] + bias;
        o = (o > 0.f) ? o : (expf(o) - 1.f);
        __builtin_nontemporal_store(o, out + (long)row * 128 + col);
      }
    }
  }
}

extern "C" void kernel_launch(void* const* d_in, const int* in_sizes, int n_in,
                              void* d_out, int out_size, void* d_ws, size_t ws_size,
                              hipStream_t stream) {
  const float* x = (const float*)d_in[0];
  const int* src = (const int*)d_in[1];
  const int* dst = (const int*)d_in[2];
  const int* et = (const int*)d_in[3];
  const float* Ww = (const float*)d_in[4];
  const float* Wres = (const float*)d_in[7];
  const float* bres = (const float*)d_in[8];
  float* out = (float*)d_out;

  const int N = in_sizes[0] / 128;  // 50000
  const int E = in_sizes[1];
  const int padM = ((N + 127) / 128) * 128;  // 50048 = 782*64
  const int NBLK = (N + 63) >> 6;            // 782

  char* ws = (char*)d_ws;
  size_t off = 0;
  auto take = [&](size_t b) {
    char* p = ws + off;
    off = (off + b + 255) & ~(size_t)255;
    return p;
  };
  __hip_bfloat16* Wb = (__hip_bfloat16*)take((size_t)1152 * 128 * 2);
  __hip_bfloat16* xb = (__hip_bfloat16*)take((size_t)padM * 128 * 2);
  int* gCount = (int*)take(NBKT * 4);
  int* coarseBase = (int*)take(NBKT * 4);
  int* tseg = (int*)take((size_t)NBLK * 9 * 4);
  int* packed2 = (int*)take((size_t)E * 4);
  int* bucketBuf = (int*)take((size_t)NBKT * CAPB * 4);

  hipMemsetAsync(gCount, 0, NBKT * 4, stream);
  k_binA<<<(E + CHUNK - 1) / CHUNK, 512, 0, stream>>>(src, dst, et, gCount, bucketBuf, E);
  k_scanC<<<1, 512, 0, stream>>>(gCount, coarseBase);
  k_sortB<<<NBLK, 512, 0, stream>>>(bucketBuf, gCount, coarseBase, packed2, tseg);
  k_wb<<<(1152 * 128 + 255) / 256, 256, 0, stream>>>(Ww, Wres, Wb);
  const int n4 = N * 128 / 4, npad4 = padM * 128 / 4;
  k_xcast<<<(npad4 + 255) / 256, 256, 0, stream>>>(x, (ushort4*)xb, n4, npad4);
  k_fused<<<NBLK, 512, 0, stream>>>((const unsigned*)xb, Wb, packed2, tseg, bres, out, N);
}

// Round 8
// 201.096 us; speedup vs baseline: 4.3672x; 4.3672x over previous
//
#include <hip/hip_runtime.h>
#include <hip/hip_bf16.h>

// out = elu(segment_sum(typed_linear(x[src], W_w, etype), dst) + x@W_res + b_res)
// (attention path of the reference is dead code)
//
// y = x @ [W_0..W_7, W_res]  ([N,128]x[128,1152] dense MFMA GEMM), then
// out[n] = elu(sum_{e: dst=n} y[src[e], et*128..] + y[n,1024..] + b_res).
// CSR over dst via two-pass LDS counting sort (256-node buckets).

#define KW 1152     // 9*128 columns of y (8 types + residual)
#define CAP 6144    // per 256-node bucket capacity (mean ~4081, +32 sigma)
#define CHUNK 2048  // edges per binning block

typedef __bf16 bf16x8 __attribute__((ext_vector_type(8)));
typedef float f32x4 __attribute__((ext_vector_type(4)));

__device__ __forceinline__ void gload_lds16(const void* g, void* l) {
  __builtin_amdgcn_global_load_lds(
      (const __attribute__((address_space(1))) unsigned int*)g,
      (__attribute__((address_space(3))) unsigned int*)l, 16, 0, 0);
}

__device__ __forceinline__ float uflo(unsigned u) { return __uint_as_float(u << 16); }
__device__ __forceinline__ float ufhi(unsigned u) { return __uint_as_float(u & 0xffff0000u); }

// ---------------- CSR pass A: coarse binning by dst>>8 ----------------
// pack27 = (src<<11) | (et<<8) | (dst&255)   (src < 65536, et < 8)
__global__ __launch_bounds__(512) void k_binA(
    const int* __restrict__ src, const int* __restrict__ dst,
    const int* __restrict__ et, int* __restrict__ gCount,
    int* __restrict__ bucketBuf, int E) {
  __shared__ int buf[CHUNK];
  __shared__ unsigned char bkt[CHUNK];
  __shared__ int h[256], ls[256], cur[256], gb[256], sc[256];
  const int tid = threadIdx.x;
  const int base = blockIdx.x * CHUNK;
  const int cnt = min(CHUNK, E - base);

  if (tid < 256) h[tid] = 0;
  __syncthreads();
  for (int j = tid; j < cnt; j += 512) atomicAdd(&h[dst[base + j] >> 8], 1);
  __syncthreads();
  if (tid < 256) sc[tid] = h[tid];
  __syncthreads();
  for (int off = 1; off < 256; off <<= 1) {
    int t = (tid < 256 && tid >= off) ? sc[tid - off] : 0;
    __syncthreads();
    if (tid < 256 && tid >= off) sc[tid] += t;
    __syncthreads();
  }
  if (tid < 256) {
    ls[tid] = sc[tid] - h[tid];
    cur[tid] = ls[tid];
    gb[tid] = (h[tid] > 0) ? atomicAdd(&gCount[tid], h[tid]) : 0;
  }
  __syncthreads();
  for (int j = tid; j < cnt; j += 512) {
    int e = base + j;
    int d = dst[e];
    int b = d >> 8;
    int pos = atomicAdd(&cur[b], 1);
    buf[pos] = (src[e] << 11) | (et[e] << 8) | (d & 255);
    bkt[pos] = (unsigned char)b;
  }
  __syncthreads();
  // bucket-grouped LDS order -> run-wise (~10 edges) coalesced global writes
  for (int j = tid; j < cnt; j += 512) {
    int b = bkt[j];
    int pos = gb[b] + (j - ls[b]);
    if (pos < CAP) bucketBuf[b * CAP + pos] = buf[j];
  }
}

// exclusive scan of 256 coarse counts; also rowstart[N] = E
__global__ __launch_bounds__(256) void k_scanC(
    const int* __restrict__ gCount, int* __restrict__ coarseBase,
    int* __restrict__ rowstart, int N, int E) {
  __shared__ int sc[256], h[256];
  int tid = threadIdx.x;
  h[tid] = gCount[tid];
  sc[tid] = h[tid];
  __syncthreads();
  for (int off = 1; off < 256; off <<= 1) {
    int t = (tid >= off) ? sc[tid - off] : 0;
    __syncthreads();
    if (tid >= off) sc[tid] += t;
    __syncthreads();
  }
  coarseBase[tid] = sc[tid] - h[tid];
  if (tid == 0) rowstart[N] = E;
}

// ---------------- CSR pass B: fine sort by dst&255 in LDS ----------------
__global__ __launch_bounds__(512) void k_sortB(
    const int* __restrict__ bucketBuf, const int* __restrict__ gCount,
    const int* __restrict__ coarseBase, int* __restrict__ rowstart,
    int* __restrict__ packed, int N) {
  __shared__ int raw[CAP];
  __shared__ int srt[CAP];
  __shared__ int h[256], sc[256], bs[256], cur[256];
  const int b = blockIdx.x;
  const int tid = threadIdx.x;
  const int cnt = min(gCount[b], CAP);
  const int base = coarseBase[b];

  if (tid < 256) h[tid] = 0;
  __syncthreads();
  for (int j = tid; j < cnt; j += 512) {
    int p = bucketBuf[b * CAP + j];
    raw[j] = p;
    atomicAdd(&h[p & 255], 1);
  }
  __syncthreads();
  if (tid < 256) sc[tid] = h[tid];
  __syncthreads();
  for (int off = 1; off < 256; off <<= 1) {
    int t = (tid < 256 && tid >= off) ? sc[tid - off] : 0;
    __syncthreads();
    if (tid < 256 && tid >= off) sc[tid] += t;
    __syncthreads();
  }
  if (tid < 256) {
    bs[tid] = sc[tid] - h[tid];
    cur[tid] = bs[tid];
    int node = b * 256 + tid;
    if (node < N) rowstart[node] = base + bs[tid];
  }
  __syncthreads();
  for (int j = tid; j < cnt; j += 512) {
    int p = raw[j];
    int pos = atomicAdd(&cur[p & 255], 1);
    srt[pos] = p;
  }
  __syncthreads();
  // packed[e] = src*144 + et*16 (uint4-unit offset of the 256B y slice)
  for (int j = tid; j < cnt; j += 512) {
    int p = srt[j];
    packed[base + j] = (p >> 11) * 144 + (((p >> 8) & 7) << 4);
  }
}

// ---------------- converts ----------------
__global__ void k_xcast(const float* __restrict__ x, ushort4* __restrict__ xb4,
                        int n4, int npad4) {
  int i = blockIdx.x * 256 + threadIdx.x;
  if (i >= npad4) return;
  ushort4 o = {0, 0, 0, 0};
  if (i < n4) {
    f32x4 v = *(const f32x4*)(x + i * 4);
    __hip_bfloat16 h0 = __float2bfloat16(v[0]), h1 = __float2bfloat16(v[1]);
    __hip_bfloat16 h2 = __float2bfloat16(v[2]), h3 = __float2bfloat16(v[3]);
    o.x = *(unsigned short*)&h0; o.y = *(unsigned short*)&h1;
    o.z = *(unsigned short*)&h2; o.w = *(unsigned short*)&h3;
  }
  xb4[i] = o;
}

// Wb row-major [1152 n][128 k]: n<1024 -> W_w[n>>7][k][n&127], else W_res[k][n&127]
__global__ void k_wb(const float* __restrict__ Ww, const float* __restrict__ Wres,
                     __hip_bfloat16* __restrict__ Wb) {
  int o = blockIdx.x * 256 + threadIdx.x;
  if (o >= KW * 128) return;
  int nn = o >> 7, kk = o & 127;
  float v = (nn < 1024) ? Ww[(nn >> 7) * 16384 + kk * 128 + (nn & 127)]
                        : Wres[kk * 128 + (nn & 127)];
  Wb[o] = __float2bfloat16(v);
}

// ---------------- y GEMM: [padM,128] x [128,1152] -> y bf16 ----------------
// grid = padM/128 row tiles; A tile staged ONCE in LDS, then loop over the 9
// 128-col weight groups (B tiles 288KB total -> always L2-hot).
// XOR swizzle ^((row&7)<<4) via pre-swizzled global source + swizzled ds_read.
__global__ __launch_bounds__(512) void k_ygemm(
    const __hip_bfloat16* __restrict__ xb, const __hip_bfloat16* __restrict__ Wb,
    unsigned short* __restrict__ y) {
  __shared__ __align__(16) unsigned short As[128 * 128];
  __shared__ __align__(16) unsigned short Bs[128 * 128];
  const int tid = threadIdx.x;
  const int lane = tid & 63;
  const int wid = tid >> 6;
  const int wr = wid >> 2, wc = wid & 3;  // 2 x 4 waves -> 64x32 per wave
  const long row0 = (long)blockIdx.x * 128;

  const char* xbb = (const char*)xb;
  const char* wbb = (const char*)Wb;
  char* asb = (char*)As;
  char* bsb = (char*)Bs;

  // stage A once
#pragma unroll
  for (int i = 0; i < 4; ++i) {
    int c = i * 512 + tid;
    int r = c >> 4, colb = (c & 15) << 4;
    int srcb = colb ^ ((r & 7) << 4);
    gload_lds16(xbb + (row0 + r) * 256 + srcb, asb + r * 256 + colb);
  }

  for (int g = 0; g < 9; ++g) {
    // stage B group g
#pragma unroll
    for (int i = 0; i < 4; ++i) {
      int c = i * 512 + tid;
      int r = c >> 4, colb = (c & 15) << 4;
      int srcb = colb ^ ((r & 7) << 4);
      gload_lds16(wbb + (long)(g * 128 + r) * 256 + srcb, bsb + r * 256 + colb);
    }
    asm volatile("s_waitcnt vmcnt(0)" ::: "memory");
    __syncthreads();

    f32x4 acc[4][2] = {};
#pragma unroll
    for (int ks = 0; ks < 4; ++ks) {
      const int cb = ks * 64 + ((lane >> 4) << 4);
      bf16x8 af[4], bfr[2];
#pragma unroll
      for (int mi = 0; mi < 4; ++mi) {
        int row = wr * 64 + mi * 16 + (lane & 15);
        af[mi] = *(const bf16x8*)(asb + ((row * 256 + cb) ^ ((row & 7) << 4)));
      }
#pragma unroll
      for (int ni = 0; ni < 2; ++ni) {
        int rowb = wc * 32 + ni * 16 + (lane & 15);
        bfr[ni] = *(const bf16x8*)(bsb + ((rowb * 256 + cb) ^ ((rowb & 7) << 4)));
      }
#pragma unroll
      for (int mi = 0; mi < 4; ++mi)
#pragma unroll
        for (int ni = 0; ni < 2; ++ni)
          acc[mi][ni] = __builtin_amdgcn_mfma_f32_16x16x32_bf16(
              af[mi], bfr[ni], acc[mi][ni], 0, 0, 0);
    }

    // C/D layout: col = lane&15, row = (lane>>4)*4 + q
#pragma unroll
    for (int mi = 0; mi < 4; ++mi)
#pragma unroll
      for (int ni = 0; ni < 2; ++ni) {
        int col = g * 128 + wc * 32 + ni * 16 + (lane & 15);
        long rb = row0 + wr * 64 + mi * 16 + ((lane >> 4) << 2);
        f32x4 v = acc[mi][ni];
#pragma unroll
        for (int q = 0; q < 4; ++q) {
          __hip_bfloat16 h = __float2bfloat16(v[q]);
          y[(rb + q) * KW + col] = *(unsigned short*)&h;
        }
      }
    __syncthreads();  // Bs reused next group
  }
}

// ---------------- scatter-sum + residual + bias + ELU ----------------
// 1 wave per node; 16 lanes x 16B per 256B edge slice -> 4 edges per load
// instruction (lane>>4 selects the edge). 32-edge chunks keep 8 gathers in
// flight; two __shfl_xor (16,32) combine the four lane-quarters.
__global__ __launch_bounds__(256) void k_scat(
    const uint4* __restrict__ y16, const int* __restrict__ rowstart,
    const int* __restrict__ packed, const float* __restrict__ bres,
    float* __restrict__ out, int N) {
  const int w = threadIdx.x >> 6, lane = threadIdx.x & 63;
  const int n = blockIdx.x * 4 + w;
  if (n >= N) return;
  const int q = lane >> 4;   // edge-in-group 0..3
  const int sub = lane & 15; // 16B element within the 256B slice
  float a[8] = {0.f, 0.f, 0.f, 0.f, 0.f, 0.f, 0.f, 0.f};
  int e = rowstart[n];
  const int end = rowstart[n + 1];

  for (; e + 32 <= end; e += 32) {
    int p[8];
    uint4 r[8];
#pragma unroll
    for (int k = 0; k < 8; ++k) p[k] = packed[e + 4 * k + q];
#pragma unroll
    for (int k = 0; k < 8; ++k) r[k] = y16[p[k] + sub];
    __builtin_amdgcn_sched_barrier(0);  // keep all 8 gathers in flight
#pragma unroll
    for (int k = 0; k < 8; ++k) {
      a[0] += uflo(r[k].x); a[1] += ufhi(r[k].x);
      a[2] += uflo(r[k].y); a[3] += ufhi(r[k].y);
      a[4] += uflo(r[k].z); a[5] += ufhi(r[k].z);
      a[6] += uflo(r[k].w); a[7] += ufhi(r[k].w);
    }
  }
  for (; e + 16 <= end; e += 16) {
    int p[4];
    uint4 r[4];
#pragma unroll
    for (int k = 0; k < 4; ++k) p[k] = packed[e + 4 * k + q];
#pragma unroll
    for (int k = 0; k < 4; ++k) r[k] = y16[p[k] + sub];
    __builtin_amdgcn_sched_barrier(0);
#pragma unroll
    for (int k = 0; k < 4; ++k) {
      a[0] += uflo(r[k].x); a[1] += ufhi(r[k].x);
      a[2] += uflo(r[k].y); a[3] += ufhi(r[k].y);
      a[4] += uflo(r[k].z); a[5] += ufhi(r[k].z);
      a[6] += uflo(r[k].w); a[7] += ufhi(r[k].w);
    }
  }
  for (; e < end; e += 4) {  // masked tail, up to 3 iterations
    int idx = e + q;
    bool v = idx < end;
    int p = packed[v ? idx : end - 1];
    uint4 r = y16[p + sub];
    if (v) {
      a[0] += uflo(r.x); a[1] += ufhi(r.x);
      a[2] += uflo(r.y); a[3] += ufhi(r.y);
      a[4] += uflo(r.z); a[5] += ufhi(r.z);
      a[6] += uflo(r.w); a[7] += ufhi(r.w);
    }
  }
#pragma unroll
  for (int i = 0; i < 8; ++i) {
    a[i] += __shfl_xor(a[i], 16);
    a[i] += __shfl_xor(a[i], 32);
  }
  // residual slice y[n, 1024..] + bias + ELU (all lanes compute; lanes<16 store)
  uint4 rr = y16[n * 144 + 128 + sub];
  a[0] += uflo(rr.x); a[1] += ufhi(rr.x);
  a[2] += uflo(rr.y); a[3] += ufhi(rr.y);
  a[4] += uflo(rr.z); a[5] += ufhi(rr.z);
  a[6] += uflo(rr.w); a[7] += ufhi(rr.w);
  f32x4 b0 = *(const f32x4*)(bres + sub * 8);
  f32x4 b1 = *(const f32x4*)(bres + sub * 8 + 4);
  f32x4 o0, o1;
#pragma unroll
  for (int i = 0; i < 4; ++i) {
    float t0 = a[i] + b0[i];
    float t1 = a[i + 4] + b1[i];
    o0[i] = t0 > 0.f ? t0 : (expf(t0) - 1.f);
    o1[i] = t1 > 0.f ? t1 : (expf(t1) - 1.f);
  }
  if (lane < 16) {
    __builtin_nontemporal_store(o0, (f32x4*)(out + (long)n * 128 + sub * 8));
    __builtin_nontemporal_store(o1, (f32x4*)(out + (long)n * 128 + sub * 8 + 4));
  }
}

extern "C" void kernel_launch(void* const* d_in, const int* in_sizes, int n_in,
                              void* d_out, int out_size, void* d_ws, size_t ws_size,
                              hipStream_t stream) {
  const float* x = (const float*)d_in[0];
  const int* src = (const int*)d_in[1];
  const int* dst = (const int*)d_in[2];
  const int* et = (const int*)d_in[3];
  const float* Ww = (const float*)d_in[4];
  const float* Wres = (const float*)d_in[7];
  const float* bres = (const float*)d_in[8];
  float* out = (float*)d_out;

  const int N = in_sizes[0] / 128;  // 50000 (< 65536 required by pack27)
  const int E = in_sizes[1];
  const int padM = ((N + 127) / 128) * 128;
  const int COARSE = (N + 255) >> 8;  // 196

  char* ws = (char*)d_ws;
  size_t off = 0;
  auto take = [&](size_t b) {
    char* p = ws + off;
    off = (off + b + 255) & ~(size_t)255;
    return p;
  };
  __hip_bfloat16* y = (__hip_bfloat16*)take((size_t)padM * KW * 2);
  __hip_bfloat16* Wb = (__hip_bfloat16*)take((size_t)KW * 128 * 2);
  __hip_bfloat16* xb = (__hip_bfloat16*)take((size_t)padM * 128 * 2);
  int* rowstart = (int*)take((size_t)(N + 1) * 4);
  int* gCount = (int*)take(256 * 4);
  int* coarseBase = (int*)take(256 * 4);
  int* packed = (int*)take((size_t)E * 4);
  // bucketBuf aliases y: consumed by k_sortB before k_ygemm writes y
  int* bucketBuf = (int*)y;  // 196*CAP*4 = 4.8 MB << y's 115 MB

  hipMemsetAsync(gCount, 0, 256 * 4, stream);
  k_binA<<<(E + CHUNK - 1) / CHUNK, 512, 0, stream>>>(src, dst, et, gCount, bucketBuf, E);
  k_scanC<<<1, 256, 0, stream>>>(gCount, coarseBase, rowstart, N, E);
  k_sortB<<<COARSE, 512, 0, stream>>>(bucketBuf, gCount, coarseBase, rowstart, packed, N);
  k_wb<<<(KW * 128 + 255) / 256, 256, 0, stream>>>(Ww, Wres, Wb);
  const int n4 = N * 128 / 4, npad4 = padM * 128 / 4;
  k_xcast<<<(npad4 + 255) / 256, 256, 0, stream>>>(x, (ushort4*)xb, n4, npad4);
  k_ygemm<<<padM / 128, 512, 0, stream>>>(xb, Wb, (unsigned short*)y);
  k_scat<<<(N + 3) / 4, 256, 0, stream>>>((const uint4*)y, rowstart, packed, bres, out, N);
}